// Round 9
// baseline (9643.888 us; speedup 1.0000x reference)
//
#include <hip/hip_runtime.h>
#include <hip/hip_bf16.h>

#define VOCAB 50000
#define EDIM 256
#define NF 128
#define KS 3
#define HID 128
#define NPATH 128
#define LSEQ 512
#define TCONV 510
#define TPOOL 509
#define CH 48   // LSTM chunk: gx(48*512*4=96KB) + x(48*128*4=24KB) + 2.5KB = 123KB LDS

typedef unsigned int uint32;

__device__ __forceinline__ uint32 bf16r(float f) {
  uint32 u = __float_as_uint(f);
  return (u + 0x7fffu + ((u >> 16) & 1u)) >> 16;   // round-to-nearest-even bf16
}
__device__ __forceinline__ uint32 pack2(float a, float b) {
  return bf16r(a) | (bf16r(b) << 16);
}
__device__ __forceinline__ float blo(uint32 w) { return __uint_as_float(w << 16); }
__device__ __forceinline__ float bhi(uint32 w) { return __uint_as_float(w & 0xffff0000u); }

__device__ __forceinline__ float sigf(float x) { return 1.f / (1.f + __expf(-x)); }
__device__ __forceinline__ float tanhf_(float x) {
  float e = __expf(2.f * x);
  return (e - 1.f) / (e + 1.f);
}

// ---------------------------------------------------------------- init:
// transpose conv weights to [e*3+k][f] for coalesced loads; u0 = emb_B[query]
__global__ void init_kernel(const float* __restrict__ conv_w,
                            const float* __restrict__ embB,
                            const int* __restrict__ query,
                            float* __restrict__ w_t, float* __restrict__ u_buf) {
  int idx = blockIdx.x * 256 + threadIdx.x;
  if (idx < EDIM * KS * NF) {
    int ek = idx >> 7, f = idx & (NF - 1);
    w_t[idx] = conv_w[f * (EDIM * KS) + ek];
  } else if (idx < EDIM * KS * NF + EDIM) {
    int i = idx - EDIM * KS * NF;
    u_buf[i] = embB[(size_t)query[0] * EDIM + i];
  }
}

// ---------------------------------------------------------------- conv:
// fused embed gather + conv1d(K=3,VALID) + bias + relu + maxpool(2,stride1)
// block = (t-tile of 32 pooled outputs, path). 256 thr: f = tid&127, th = tid>>7.
__global__ __launch_bounds__(256) void conv_kernel(
    const int* __restrict__ path, const float* __restrict__ embA,
    const float* __restrict__ w_t, const float* __restrict__ conv_b,
    float* __restrict__ pooled) {
  __shared__ float xs[35 * EDIM];
  int t0 = blockIdx.x * 32;
  int p = blockIdx.y;
  const int* prow = path + p * LSEQ;
  for (int tok = 0; tok < 35; ++tok) {
    int tt = t0 + tok;
    float v = 0.f;
    if (tt < LSEQ) v = embA[(size_t)prow[tt] * EDIM + threadIdx.x];
    xs[tok * EDIM + threadIdx.x] = v;
  }
  __syncthreads();
  int f = threadIdx.x & (NF - 1), th = threadIdx.x >> 7;
  float b = conv_b[f];
  float acc[17];
#pragma unroll
  for (int i = 0; i < 17; ++i) acc[i] = b;
  for (int e = 0; e < EDIM; ++e) {
    float xv[19];
#pragma unroll
    for (int j = 0; j < 19; ++j) xv[j] = xs[(th * 16 + j) * EDIM + e];  // broadcast
#pragma unroll
    for (int k = 0; k < KS; ++k) {
      float wv = w_t[(e * KS + k) * NF + f];  // coalesced, L2-resident (393KB)
#pragma unroll
      for (int i = 0; i < 17; ++i) acc[i] += wv * xv[i + k];
    }
  }
#pragma unroll
  for (int i = 0; i < 16; ++i) {
    int t = t0 + th * 16 + i;
    if (t < TPOOL) {
      float v = fmaxf(fmaxf(acc[i], 0.f), fmaxf(acc[i + 1], 0.f));
      pooled[((size_t)p * TPOOL + t) * NF + f] = v;
    }
  }
}

// ---------------------------------------------------------------- lstm:
// one block per (path, direction), 512 thr, thread g owns gate g.
// Rounds 1-7 evidence: the allocator pins this kernel at 128 VGPRs no matter
// what launch_bounds says; holding BOTH weight matrices (128 packed regs)
// spills -> 2.3 GB HBM refetch/dispatch. Fix: chunked time-share of ONE
// 64-reg weight block. Per 48-step chunk:
//   phase 1: stage x chunk to LDS; load w_ih into wreg[64];
//            gx[j][g] = bias + w_ih_g . x_j   (parallel over threads, no dep)
//   phase 2: overwrite wreg with w_hh; 48 recurrent steps: only h-dot serial.
// Live regs ~105 < 128 -> no spill; serial FMAs per step halve (256 -> 128).
__global__ __launch_bounds__(512, 1) void lstm_kernel(
    const float* __restrict__ pooled,
    const float* __restrict__ w_ih_f, const float* __restrict__ w_hh_f,
    const float* __restrict__ b_ih_f, const float* __restrict__ b_hh_f,
    const float* __restrict__ w_ih_b, const float* __restrict__ w_hh_b,
    const float* __restrict__ b_ih_b, const float* __restrict__ b_hh_b,
    float* __restrict__ context) {
  __shared__ __align__(16) float x_l[CH][NF];    // 24 KB, step-ordered x chunk
  __shared__ __align__(16) float gx[CH][4 * HID]; // 96 KB, precomputed input gates
  __shared__ __align__(16) float h_l[HID];
  __shared__ float g_l[4 * HID];
  int p = blockIdx.x >> 1, d = blockIdx.x & 1;
  const float* w_ih = d ? w_ih_b : w_ih_f;
  const float* w_hh = d ? w_hh_b : w_hh_f;
  const float* b_ih = d ? b_ih_b : b_ih_f;
  const float* b_hh = d ? b_hh_b : b_hh_f;
  int g = threadIdx.x;
  float bias = b_ih[g] + b_hh[g];
  const float* prow = pooled + (size_t)p * TPOOL * NF;
  float c = 0.f, h = 0.f;
  if (g < HID) h_l[g] = 0.f;
  uint32 wreg[64];

  for (int t0 = 0; t0 < TPOOL; t0 += CH) {
    int ns = (TPOOL - t0 < CH) ? (TPOOL - t0) : CH;
    // ---- stage x chunk (coalesced float4); all threads past prev chunk's
    // final barrier, so x_l/gx are free to overwrite.
    for (int q = g; q < ns * (NF / 4); q += 512) {
      int j = q >> 5, e4 = q & 31;
      int ti = d ? (TPOOL - 1 - (t0 + j)) : (t0 + j);
      *(float4*)&x_l[j][e4 * 4] = *(const float4*)(prow + ti * NF + e4 * 4);
    }
    // ---- load w_ih into the shared weight regs (overlaps staging latency)
#pragma unroll
    for (int jj = 0; jj < 32; ++jj) {
      float4 a = *(const float4*)(w_ih + g * HID + 4 * jj);
      wreg[2 * jj] = pack2(a.x, a.y);
      wreg[2 * jj + 1] = pack2(a.z, a.w);
    }
    __syncthreads();  // x_l ready
    // ---- phase 1: input-gate precompute (parallel, no serial dependency)
    for (int j = 0; j < ns; ++j) {
      float a0 = bias, a1 = 0.f, a2 = 0.f, a3 = 0.f;
      const float4* x4 = (const float4*)x_l[j];
#pragma unroll
      for (int jj = 0; jj < 32; ++jj) {
        float4 xv = x4[jj];
        uint32 wa = wreg[2 * jj], wb = wreg[2 * jj + 1];
        a0 += blo(wa) * xv.x;
        a1 += bhi(wa) * xv.y;
        a2 += blo(wb) * xv.z;
        a3 += bhi(wb) * xv.w;
      }
      gx[j][g] = (a0 + a1) + (a2 + a3);
    }
    // ---- swap weights: same 64 regs now hold w_hh (overlaps gx tail)
#pragma unroll
    for (int jj = 0; jj < 32; ++jj) {
      float4 a = *(const float4*)(w_hh + g * HID + 4 * jj);
      wreg[2 * jj] = pack2(a.x, a.y);
      wreg[2 * jj + 1] = pack2(a.z, a.w);
    }
    __syncthreads();  // gx complete (h_l valid from prev chunk)
    // ---- phase 2: recurrence, h-dot only
    for (int j = 0; j < ns; ++j) {
      float a0 = gx[j][g], a1 = 0.f, a2 = 0.f, a3 = 0.f;
      const float4* h4 = (const float4*)h_l;
#pragma unroll
      for (int jj = 0; jj < 32; ++jj) {
        float4 hv = h4[jj];
        uint32 wa = wreg[2 * jj], wb = wreg[2 * jj + 1];
        a0 += blo(wa) * hv.x;
        a1 += bhi(wa) * hv.y;
        a2 += blo(wb) * hv.z;
        a3 += bhi(wb) * hv.w;
      }
      g_l[g] = (a0 + a1) + (a2 + a3);
      __syncthreads();  // gates complete
      if (g < HID) {
        float gi = g_l[g], gf = g_l[HID + g], gg = g_l[2 * HID + g],
              go = g_l[3 * HID + g];
        c = sigf(gf) * c + sigf(gi) * tanhf_(gg);
        h = sigf(go) * tanhf_(c);
        h_l[g] = h;
      }
      __syncthreads();  // h_l ready for next step
    }
  }
  if (g < HID) context[p * 2 * HID + d * HID + g] = h;
}

// ---------------------------------------------------------------- attention
__global__ __launch_bounds__(256) void score_kernel(
    const float* __restrict__ context, const float* __restrict__ u_buf,
    const float* __restrict__ d1_w, const float* __restrict__ d1_b,
    const float* __restrict__ d2_w, const float* __restrict__ d2_b,
    float* __restrict__ scores) {
  __shared__ __align__(16) float cat[2 * EDIM];
  __shared__ float red[4];
  int p = blockIdx.x;
  int i = threadIdx.x;
  cat[i] = context[p * 2 * HID + i];
  cat[EDIM + i] = u_buf[i];
  __syncthreads();
  float acc = d1_b[i];
  const float4* wrow = (const float4*)(d1_w + (size_t)i * 2 * EDIM);
#pragma unroll 8
  for (int j = 0; j < 128; ++j) {
    float4 w4 = wrow[j];
    float4 c4 = *(const float4*)(&cat[4 * j]);
    acc += w4.x * c4.x + w4.y * c4.y + w4.z * c4.z + w4.w * c4.w;
  }
  float v = tanhf_(acc) * d2_w[i];
#pragma unroll
  for (int o = 32; o; o >>= 1) v += __shfl_down(v, o, 64);
  int lane = i & 63, w = i >> 6;
  if (lane == 0) red[w] = v;
  __syncthreads();
  if (i == 0) scores[p] = red[0] + red[1] + red[2] + red[3] + d2_b[0];
}

__global__ __launch_bounds__(256) void reduce_kernel(
    const float* __restrict__ context, const float* __restrict__ d1_w,
    const float* __restrict__ d1_b, const float* __restrict__ d2_w,
    const float* __restrict__ d2_b, const float* __restrict__ scores,
    float* __restrict__ u_buf, float* __restrict__ out, int final_step) {
  __shared__ float al[NPATH];
  __shared__ __align__(16) float uo[2 * EDIM];
  __shared__ float red[4];
  int i = threadIdx.x;
  int lane = i & 63, w = i >> 6;

  // softmax over 128 path scores
  float s = (i < NPATH) ? scores[i] : -1e30f;
  float m = s;
#pragma unroll
  for (int o = 32; o; o >>= 1) m = fmaxf(m, __shfl_down(m, o, 64));
  if (lane == 0) red[w] = m;
  __syncthreads();
  m = fmaxf(fmaxf(red[0], red[1]), fmaxf(red[2], red[3]));
  __syncthreads();
  float e = (i < NPATH) ? __expf(s - m) : 0.f;
  float t = e;
#pragma unroll
  for (int o = 32; o; o >>= 1) t += __shfl_down(t, o, 64);
  if (lane == 0) red[w] = t;
  __syncthreads();
  float sum = red[0] + red[1] + red[2] + red[3];
  if (i < NPATH) al[i] = e / sum;
  __syncthreads();

  // o = sum_p alpha[p] * context[p]  (i in 0..255)
  float o_i = 0.f;
  for (int p = 0; p < NPATH; ++p) o_i += al[p] * context[p * 2 * HID + i];
  uo[i] = u_buf[i];
  uo[EDIM + i] = o_i;
  __syncthreads();

  // u_new = [u;o] @ d1_w.T + d1_b
  float un = d1_b[i];
  const float4* wrow = (const float4*)(d1_w + (size_t)i * 2 * EDIM);
#pragma unroll 8
  for (int j = 0; j < 128; ++j) {
    float4 w4 = wrow[j];
    float4 c4 = *(const float4*)(&uo[4 * j]);
    un += w4.x * c4.x + w4.y * c4.y + w4.z * c4.z + w4.w * c4.w;
  }
  if (!final_step) {
    u_buf[i] = un;
  } else {
    float v = fmaxf(un, 0.f) * d2_w[i];
#pragma unroll
    for (int o = 32; o; o >>= 1) v += __shfl_down(v, o, 64);
    if (lane == 0) red[w] = v;
    __syncthreads();
    if (i == 0) {
      float tot = red[0] + red[1] + red[2] + red[3] + d2_b[0];
      out[0] = 1.f / (1.f + __expf(-tot));
    }
  }
}

// ----------------------------------------------------------------
extern "C" void kernel_launch(void* const* d_in, const int* in_sizes, int n_in,
                              void* d_out, int out_size, void* d_ws, size_t ws_size,
                              hipStream_t stream) {
  const int* path = (const int*)d_in[0];
  const int* query = (const int*)d_in[1];
  const float* embA = (const float*)d_in[2];
  const float* embB = (const float*)d_in[3];
  const float* conv_w = (const float*)d_in[4];
  const float* conv_b = (const float*)d_in[5];
  const float* w_ih_f = (const float*)d_in[6];
  const float* w_hh_f = (const float*)d_in[7];
  const float* b_ih_f = (const float*)d_in[8];
  const float* b_hh_f = (const float*)d_in[9];
  const float* w_ih_b = (const float*)d_in[10];
  const float* w_hh_b = (const float*)d_in[11];
  const float* b_ih_b = (const float*)d_in[12];
  const float* b_hh_b = (const float*)d_in[13];
  const float* d1_w = (const float*)d_in[14];
  const float* d1_b = (const float*)d_in[15];
  const float* d2_w = (const float*)d_in[16];
  const float* d2_b = (const float*)d_in[17];
  float* out = (float*)d_out;

  float* ws = (float*)d_ws;
  float* pooled = ws;                                     // 128*509*128
  float* w_t = pooled + (size_t)NPATH * TPOOL * NF;       // 768*128
  float* context = w_t + EDIM * KS * NF;                  // 128*256
  float* scores = context + NPATH * 2 * HID;              // 128
  float* u_buf = scores + NPATH;                          // 256

  init_kernel<<<(EDIM * KS * NF + EDIM + 255) / 256, 256, 0, stream>>>(
      conv_w, embB, query, w_t, u_buf);
  conv_kernel<<<dim3(16, NPATH), 256, 0, stream>>>(path, embA, w_t, conv_b,
                                                   pooled);
  lstm_kernel<<<256, 512, 0, stream>>>(pooled, w_ih_f, w_hh_f, b_ih_f, b_hh_f,
                                       w_ih_b, w_hh_b, b_ih_b, b_hh_b, context);
  score_kernel<<<NPATH, 256, 0, stream>>>(context, u_buf, d1_w, d1_b, d2_w,
                                          d2_b, scores);
  reduce_kernel<<<1, 256, 0, stream>>>(context, d1_w, d1_b, d2_w, d2_b, scores,
                                       u_buf, out, 0);
  score_kernel<<<NPATH, 256, 0, stream>>>(context, u_buf, d1_w, d1_b, d2_w,
                                          d2_b, scores);
  reduce_kernel<<<1, 256, 0, stream>>>(context, d1_w, d1_b, d2_w, d2_b, scores,
                                       u_buf, out, 1);
}

// Round 11
// 2036.359 us; speedup vs baseline: 4.7358x; 4.7358x over previous
//
#include <hip/hip_runtime.h>
#include <hip/hip_bf16.h>

#define VOCAB 50000
#define EDIM 256
#define NF 128
#define KS 3
#define HID 128
#define NPATH 128
#define LSEQ 512
#define TCONV 510
#define TPOOL 509
#define CH 48   // LSTM chunk: gx(48*512*4=96KB) + x(48*128*4=24KB) + 2.5KB = 123KB LDS

typedef unsigned int uint32;

__device__ __forceinline__ uint32 bf16r(float f) {
  uint32 u = __float_as_uint(f);
  return (u + 0x7fffu + ((u >> 16) & 1u)) >> 16;   // round-to-nearest-even bf16
}
__device__ __forceinline__ uint32 pack2(float a, float b) {
  return bf16r(a) | (bf16r(b) << 16);
}
__device__ __forceinline__ float blo(uint32 w) { return __uint_as_float(w << 16); }
__device__ __forceinline__ float bhi(uint32 w) { return __uint_as_float(w & 0xffff0000u); }

__device__ __forceinline__ float sigf(float x) { return 1.f / (1.f + __expf(-x)); }
__device__ __forceinline__ float tanhf_(float x) {
  float e = __expf(2.f * x);
  return (e - 1.f) / (e + 1.f);
}

// ---------------------------------------------------------------- init:
// transpose conv weights to [e*3+k][f] for coalesced loads; u0 = emb_B[query]
__global__ void init_kernel(const float* __restrict__ conv_w,
                            const float* __restrict__ embB,
                            const int* __restrict__ query,
                            float* __restrict__ w_t, float* __restrict__ u_buf) {
  int idx = blockIdx.x * 256 + threadIdx.x;
  if (idx < EDIM * KS * NF) {
    int ek = idx >> 7, f = idx & (NF - 1);
    w_t[idx] = conv_w[f * (EDIM * KS) + ek];
  } else if (idx < EDIM * KS * NF + EDIM) {
    int i = idx - EDIM * KS * NF;
    u_buf[i] = embB[(size_t)query[0] * EDIM + i];
  }
}

// ---------------------------------------------------------------- conv:
// fused embed gather + conv1d(K=3,VALID) + bias + relu + maxpool(2,stride1)
// block = (t-tile of 32 pooled outputs, path). 256 thr: f = tid&127, th = tid>>7.
__global__ __launch_bounds__(256) void conv_kernel(
    const int* __restrict__ path, const float* __restrict__ embA,
    const float* __restrict__ w_t, const float* __restrict__ conv_b,
    float* __restrict__ pooled) {
  __shared__ float xs[35 * EDIM];
  int t0 = blockIdx.x * 32;
  int p = blockIdx.y;
  const int* prow = path + p * LSEQ;
  for (int tok = 0; tok < 35; ++tok) {
    int tt = t0 + tok;
    float v = 0.f;
    if (tt < LSEQ) v = embA[(size_t)prow[tt] * EDIM + threadIdx.x];
    xs[tok * EDIM + threadIdx.x] = v;
  }
  __syncthreads();
  int f = threadIdx.x & (NF - 1), th = threadIdx.x >> 7;
  float b = conv_b[f];
  float acc[17];
#pragma unroll
  for (int i = 0; i < 17; ++i) acc[i] = b;
  for (int e = 0; e < EDIM; ++e) {
    float xv[19];
#pragma unroll
    for (int j = 0; j < 19; ++j) xv[j] = xs[(th * 16 + j) * EDIM + e];  // broadcast
#pragma unroll
    for (int k = 0; k < KS; ++k) {
      float wv = w_t[(e * KS + k) * NF + f];  // coalesced, L2-resident (393KB)
#pragma unroll
      for (int i = 0; i < 17; ++i) acc[i] += wv * xv[i + k];
    }
  }
#pragma unroll
  for (int i = 0; i < 16; ++i) {
    int t = t0 + th * 16 + i;
    if (t < TPOOL) {
      float v = fmaxf(fmaxf(acc[i], 0.f), fmaxf(acc[i + 1], 0.f));
      pooled[((size_t)p * TPOOL + t) * NF + f] = v;
    }
  }
}

// ---------------------------------------------------------------- lstm:
// one block per (path, direction), 512 thr.
// Rounds 1-9 evidence: allocator pins 128 VGPRs; >110 live regs or in-loop
// reloads of a reg array -> permanent scratch residency (r9: 19.5 GB fetch).
// Design for <=128 regs by construction:
//  - ONLY w_hh is register-resident (64 packed-bf16 regs), loaded ONCE at
//    start in sched-barrier'd groups of 8 (caps transient pressure).
//  - per 48-step chunk, phase 1 computes gx = bias + x @ w_ih^T into LDS with
//    a (4 gates x 4 steps) tile, STREAMING w_ih from L2 (no weight regs;
//    acc16 + w16 + x4 transient ~50 regs). thread (gq=tid&127, jq=tid>>7)
//    owns gates 4gq..4gq+3 and j in [jq*12, jq*12+12).
//  - phase 2 recurrence: a = gx_l[j][tid] + w_hh_row . h (h broadcast from
//    LDS); 128 MAC/step/thread, half the old serial work.
__global__ __launch_bounds__(512, 1) void lstm_kernel(
    const float* __restrict__ pooled,
    const float* __restrict__ w_ih_f, const float* __restrict__ w_hh_f,
    const float* __restrict__ b_ih_f, const float* __restrict__ b_hh_f,
    const float* __restrict__ w_ih_b, const float* __restrict__ w_hh_b,
    const float* __restrict__ b_ih_b, const float* __restrict__ b_hh_b,
    float* __restrict__ context) {
  __shared__ __align__(16) float x_l[CH][NF];       // 24 KB
  __shared__ __align__(16) float gx_l[CH][4 * HID]; // 96 KB
  __shared__ __align__(16) float h_l[HID];
  __shared__ float g_l[4 * HID];
  int p = blockIdx.x >> 1, d = blockIdx.x & 1;
  const float* w_ih = d ? w_ih_b : w_ih_f;
  const float* w_hh = d ? w_hh_b : w_hh_f;
  const float* b_ih = d ? b_ih_b : b_ih_f;
  const float* b_hh = d ? b_hh_b : b_hh_f;
  int tid = threadIdx.x;
  int gq = tid & 127, jq = tid >> 7;

  // persistent packed w_hh row for gate `tid` — single load site, grouped to
  // cap in-flight dest registers at 32.
  uint32 whh[64];
#pragma unroll
  for (int grp = 0; grp < 4; ++grp) {
#pragma unroll
    for (int q = 0; q < 8; ++q) {
      int jj = grp * 8 + q;
      float4 a = *(const float4*)(w_hh + (size_t)tid * HID + 4 * jj);
      whh[2 * jj] = pack2(a.x, a.y);
      whh[2 * jj + 1] = pack2(a.z, a.w);
    }
    __builtin_amdgcn_sched_barrier(0);
  }
  // biases for this thread's 4 phase-1 gates
  float bias4[4];
#pragma unroll
  for (int gi = 0; gi < 4; ++gi)
    bias4[gi] = b_ih[4 * gq + gi] + b_hh[4 * gq + gi];

  float c = 0.f, h = 0.f;
  if (tid < HID) h_l[tid] = 0.f;
  const float* prow = pooled + (size_t)p * TPOOL * NF;

  for (int t0 = 0; t0 < TPOOL; t0 += CH) {
    int ns = (TPOOL - t0 < CH) ? (TPOOL - t0) : CH;
    // ---- stage x chunk (coalesced float4)
    for (int q = tid; q < ns * (NF / 4); q += 512) {
      int j = q >> 5, e4 = q & 31;
      int ti = d ? (TPOOL - 1 - (t0 + j)) : (t0 + j);
      *(float4*)&x_l[j][e4 * 4] = *(const float4*)(prow + ti * NF + e4 * 4);
    }
    __syncthreads();  // x_l ready (prev chunk fully done: step-loop barriers)
    // ---- phase 1: gx tile (4 gates x 4 steps), w_ih streamed from L2
    const float* wbase = w_ih + (size_t)(4 * gq) * HID;
    for (int ps = 0; ps < 3; ++ps) {
      int jb = jq * 12 + ps * 4;
      float acc[4][4];
#pragma unroll
      for (int ji = 0; ji < 4; ++ji)
#pragma unroll
        for (int gi = 0; gi < 4; ++gi) acc[ji][gi] = bias4[gi];
      for (int jj = 0; jj < 32; ++jj) {  // runtime loop: caps reg pressure
        float4 w0 = *(const float4*)(wbase + 0 * HID + 4 * jj);
        float4 w1 = *(const float4*)(wbase + 1 * HID + 4 * jj);
        float4 w2 = *(const float4*)(wbase + 2 * HID + 4 * jj);
        float4 w3 = *(const float4*)(wbase + 3 * HID + 4 * jj);
#pragma unroll
        for (int ji = 0; ji < 4; ++ji) {
          float4 xv = *(const float4*)&x_l[jb + ji][4 * jj];  // LDS broadcast
          acc[ji][0] += w0.x * xv.x + w0.y * xv.y + w0.z * xv.z + w0.w * xv.w;
          acc[ji][1] += w1.x * xv.x + w1.y * xv.y + w1.z * xv.z + w1.w * xv.w;
          acc[ji][2] += w2.x * xv.x + w2.y * xv.y + w2.z * xv.z + w2.w * xv.w;
          acc[ji][3] += w3.x * xv.x + w3.y * xv.y + w3.z * xv.z + w3.w * xv.w;
        }
      }
#pragma unroll
      for (int ji = 0; ji < 4; ++ji)
        if (jb + ji < ns)
          *(float4*)&gx_l[jb + ji][4 * gq] =
              make_float4(acc[ji][0], acc[ji][1], acc[ji][2], acc[ji][3]);
    }
    __syncthreads();  // gx complete
    // ---- phase 2: recurrence (h-dot only)
    for (int j = 0; j < ns; ++j) {
      float a0 = gx_l[j][tid], a1 = 0.f, a2 = 0.f, a3 = 0.f;
      const float4* h4 = (const float4*)h_l;
#pragma unroll
      for (int jj = 0; jj < 32; ++jj) {
        float4 hv = h4[jj];
        uint32 wa = whh[2 * jj], wb = whh[2 * jj + 1];
        a0 += blo(wa) * hv.x;
        a1 += bhi(wa) * hv.y;
        a2 += blo(wb) * hv.z;
        a3 += bhi(wb) * hv.w;
      }
      g_l[tid] = (a0 + a1) + (a2 + a3);
      __syncthreads();  // gates complete
      if (tid < HID) {
        float gi = g_l[tid], gf = g_l[HID + tid], gg = g_l[2 * HID + tid],
              go = g_l[3 * HID + tid];
        c = sigf(gf) * c + sigf(gi) * tanhf_(gg);
        h = sigf(go) * tanhf_(c);
        h_l[tid] = h;
      }
      __syncthreads();  // h_l ready for next step
    }
  }
  if (tid < HID) context[p * 2 * HID + d * HID + tid] = h;
}

// ---------------------------------------------------------------- attention
__global__ __launch_bounds__(256) void score_kernel(
    const float* __restrict__ context, const float* __restrict__ u_buf,
    const float* __restrict__ d1_w, const float* __restrict__ d1_b,
    const float* __restrict__ d2_w, const float* __restrict__ d2_b,
    float* __restrict__ scores) {
  __shared__ __align__(16) float cat[2 * EDIM];
  __shared__ float red[4];
  int p = blockIdx.x;
  int i = threadIdx.x;
  cat[i] = context[p * 2 * HID + i];
  cat[EDIM + i] = u_buf[i];
  __syncthreads();
  float acc = d1_b[i];
  const float4* wrow = (const float4*)(d1_w + (size_t)i * 2 * EDIM);
#pragma unroll 8
  for (int j = 0; j < 128; ++j) {
    float4 w4 = wrow[j];
    float4 c4 = *(const float4*)(&cat[4 * j]);
    acc += w4.x * c4.x + w4.y * c4.y + w4.z * c4.z + w4.w * c4.w;
  }
  float v = tanhf_(acc) * d2_w[i];
#pragma unroll
  for (int o = 32; o; o >>= 1) v += __shfl_down(v, o, 64);
  int lane = i & 63, w = i >> 6;
  if (lane == 0) red[w] = v;
  __syncthreads();
  if (i == 0) scores[p] = red[0] + red[1] + red[2] + red[3] + d2_b[0];
}

__global__ __launch_bounds__(256) void reduce_kernel(
    const float* __restrict__ context, const float* __restrict__ d1_w,
    const float* __restrict__ d1_b, const float* __restrict__ d2_w,
    const float* __restrict__ d2_b, const float* __restrict__ scores,
    float* __restrict__ u_buf, float* __restrict__ out, int final_step) {
  __shared__ float al[NPATH];
  __shared__ __align__(16) float uo[2 * EDIM];
  __shared__ float red[4];
  int i = threadIdx.x;
  int lane = i & 63, w = i >> 6;

  // softmax over 128 path scores
  float s = (i < NPATH) ? scores[i] : -1e30f;
  float m = s;
#pragma unroll
  for (int o = 32; o; o >>= 1) m = fmaxf(m, __shfl_down(m, o, 64));
  if (lane == 0) red[w] = m;
  __syncthreads();
  m = fmaxf(fmaxf(red[0], red[1]), fmaxf(red[2], red[3]));
  __syncthreads();
  float e = (i < NPATH) ? __expf(s - m) : 0.f;
  float t = e;
#pragma unroll
  for (int o = 32; o; o >>= 1) t += __shfl_down(t, o, 64);
  if (lane == 0) red[w] = t;
  __syncthreads();
  float sum = red[0] + red[1] + red[2] + red[3];
  if (i < NPATH) al[i] = e / sum;
  __syncthreads();

  // o = sum_p alpha[p] * context[p]  (i in 0..255)
  float o_i = 0.f;
  for (int p = 0; p < NPATH; ++p) o_i += al[p] * context[p * 2 * HID + i];
  uo[i] = u_buf[i];
  uo[EDIM + i] = o_i;
  __syncthreads();

  // u_new = [u;o] @ d1_w.T + d1_b
  float un = d1_b[i];
  const float4* wrow = (const float4*)(d1_w + (size_t)i * 2 * EDIM);
#pragma unroll 8
  for (int j = 0; j < 128; ++j) {
    float4 w4 = wrow[j];
    float4 c4 = *(const float4*)(&uo[4 * j]);
    un += w4.x * c4.x + w4.y * c4.y + w4.z * c4.z + w4.w * c4.w;
  }
  if (!final_step) {
    u_buf[i] = un;
  } else {
    float v = fmaxf(un, 0.f) * d2_w[i];
#pragma unroll
    for (int o = 32; o; o >>= 1) v += __shfl_down(v, o, 64);
    if (lane == 0) red[w] = v;
    __syncthreads();
    if (i == 0) {
      float tot = red[0] + red[1] + red[2] + red[3] + d2_b[0];
      out[0] = 1.f / (1.f + __expf(-tot));
    }
  }
}

// ----------------------------------------------------------------
extern "C" void kernel_launch(void* const* d_in, const int* in_sizes, int n_in,
                              void* d_out, int out_size, void* d_ws, size_t ws_size,
                              hipStream_t stream) {
  const int* path = (const int*)d_in[0];
  const int* query = (const int*)d_in[1];
  const float* embA = (const float*)d_in[2];
  const float* embB = (const float*)d_in[3];
  const float* conv_w = (const float*)d_in[4];
  const float* conv_b = (const float*)d_in[5];
  const float* w_ih_f = (const float*)d_in[6];
  const float* w_hh_f = (const float*)d_in[7];
  const float* b_ih_f = (const float*)d_in[8];
  const float* b_hh_f = (const float*)d_in[9];
  const float* w_ih_b = (const float*)d_in[10];
  const float* w_hh_b = (const float*)d_in[11];
  const float* b_ih_b = (const float*)d_in[12];
  const float* b_hh_b = (const float*)d_in[13];
  const float* d1_w = (const float*)d_in[14];
  const float* d1_b = (const float*)d_in[15];
  const float* d2_w = (const float*)d_in[16];
  const float* d2_b = (const float*)d_in[17];
  float* out = (float*)d_out;

  float* ws = (float*)d_ws;
  float* pooled = ws;                                     // 128*509*128
  float* w_t = pooled + (size_t)NPATH * TPOOL * NF;       // 768*128
  float* context = w_t + EDIM * KS * NF;                  // 128*256
  float* scores = context + NPATH * 2 * HID;              // 128
  float* u_buf = scores + NPATH;                          // 256

  init_kernel<<<(EDIM * KS * NF + EDIM + 255) / 256, 256, 0, stream>>>(
      conv_w, embB, query, w_t, u_buf);
  conv_kernel<<<dim3(16, NPATH), 256, 0, stream>>>(path, embA, w_t, conv_b,
                                                   pooled);
  lstm_kernel<<<256, 512, 0, stream>>>(pooled, w_ih_f, w_hh_f, b_ih_f, b_hh_f,
                                       w_ih_b, w_hh_b, b_ih_b, b_hh_b, context);
  score_kernel<<<NPATH, 256, 0, stream>>>(context, u_buf, d1_w, d1_b, d2_w,
                                          d2_b, scores);
  reduce_kernel<<<1, 256, 0, stream>>>(context, d1_w, d1_b, d2_w, d2_b, scores,
                                       u_buf, out, 0);
  score_kernel<<<NPATH, 256, 0, stream>>>(context, u_buf, d1_w, d1_b, d2_w,
                                          d2_b, scores);
  reduce_kernel<<<1, 256, 0, stream>>>(context, d1_w, d1_b, d2_w, d2_b, scores,
                                       u_buf, out, 1);
}